// Round 1
// baseline (2152.666 us; speedup 1.0000x reference)
//
#include <hip/hip_runtime.h>
#include <math.h>

#define DIMC 512
#define NG 8

// ---------------- Wo (512x512) -> WoT transpose ----------------
__global__ __launch_bounds__(256) void k_wot(const float* __restrict__ Wo, float* __restrict__ WoT) {
    __shared__ float tile[32][33];
    int bx = blockIdx.x, by = blockIdx.y;
    int tx = threadIdx.x & 31, ty = threadIdx.x >> 5;  // 32x8
#pragma unroll
    for (int r = 0; r < 4; ++r)
        tile[ty + r*8][tx] = Wo[(size_t)(by*32 + ty + r*8)*DIMC + bx*32 + tx];
    __syncthreads();
#pragma unroll
    for (int r = 0; r < 4; ++r)
        WoT[(size_t)(bx*32 + ty + r*8)*DIMC + by*32 + tx] = tile[tx][ty + r*8];
}

// ---------------- q = grouped 1x1 conv over concat[prev_x, x] ----------------
// q stored channel-major: q[oc*n + i], oc in [0,512)
__global__ __launch_bounds__(256) void k_qconv(
    const float* __restrict__ x, const float* __restrict__ px,
    const float* __restrict__ Wq, float* __restrict__ q, int n)
{
    __shared__ float Xs[64][129];   // [i][k], pad-> lane-varying b32 reads conflict-free
    __shared__ float Wt[128][68];   // [k][oc], 68 keeps rows 16B aligned for f4 broadcast
    int g  = blockIdx.x;            // 0..7
    int i0 = blockIdx.y * 64;
    int t  = threadIdx.x;
    const float* SRC = (g < 4) ? px : x;   // concat puts prev first
    int cbase = (g & 3) * 128;
#pragma unroll
    for (int r = 0; r < 8; ++r) {          // 64 i x 32 f4 over k
        int f = t + 256*r;
        int i = f >> 5, kq = f & 31;
        float4 v = *(const float4*)&SRC[(size_t)(i0+i)*DIMC + cbase + kq*4];
        Xs[i][kq*4+0] = v.x; Xs[i][kq*4+1] = v.y; Xs[i][kq*4+2] = v.z; Xs[i][kq*4+3] = v.w;
    }
#pragma unroll
    for (int r = 0; r < 32; ++r) {         // 8192 scalars: transpose W into [k][oc]
        int f = t + 256*r;
        int oc = f & 63, kk = f >> 6;
        Wt[kk][oc] = Wq[(size_t)(g*64+oc)*128 + kk];
    }
    __syncthreads();
    int lane = t & 63, w = t >> 6;         // lane = i, wave owns 16 oc
    float acc[16];
#pragma unroll
    for (int u = 0; u < 16; ++u) acc[u] = 0.f;
#pragma unroll 4
    for (int k = 0; k < 128; ++k) {
        float xv = Xs[lane][k];
#pragma unroll
        for (int q4 = 0; q4 < 4; ++q4) {
            float4 wv = *(const float4*)&Wt[k][w*16 + q4*4];   // broadcast
            acc[q4*4+0] += xv*wv.x; acc[q4*4+1] += xv*wv.y;
            acc[q4*4+2] += xv*wv.z; acc[q4*4+3] += xv*wv.w;
        }
    }
#pragma unroll
    for (int u = 0; u < 16; ++u)           // coalesced over lane=i
        q[(size_t)(g*64 + w*16 + u)*n + i0 + lane] = acc[u];
}

// ---------------- offset net: depthwise conv s4 + GELU + 1x1 + tanh -> sample pos ----------------
__global__ __launch_bounds__(256) void k_off(
    const float* __restrict__ q, const float* __restrict__ Wdw,
    const float* __restrict__ bdw, const float* __restrict__ Wp,
    int* __restrict__ x0i, float* __restrict__ w1f, int n, int m)
{
    int idx = blockIdx.x*256 + threadIdx.x;
    if (idx >= NG*m) return;
    int gg = idx / m, j = idx - gg*m;
    float off = 0.f;
    for (int c = 0; c < 64; ++c) {
        float h = bdw[c];
        const float* qrow = &q[(size_t)(gg*64 + c)*n];
#pragma unroll
        for (int tt = 0; tt < 6; ++tt) {
            int p = 4*j - 1 + tt;                 // stride 4, pad 1
            if (p >= 0 && p < n) h += Wdw[c*6 + tt] * qrow[p];
        }
        float ge = 0.5f * h * (1.0f + erff(h * 0.70710678118654752f));  // exact gelu
        off += Wp[c] * ge;
    }
    off = tanhf(off) * 4.0f;
    // replicate reference op order exactly
    float vg  = 2.0f * ((float)j + off) / (float)(m - 1) - 1.0f;
    float pos = ((vg + 1.0f) * (float)n - 1.0f) * 0.5f;
    float x0  = floorf(pos);
    x0i[idx] = (int)x0;
    w1f[idx] = pos - x0;
}

// ---------------- grid-sample + k/v grouped 1x1 convs ----------------
// kt/vt stored as [s][h][j][d] for coalesced attention staging
__global__ __launch_bounds__(256) void k_kv(
    const float* __restrict__ x, const float* __restrict__ px,
    const float* __restrict__ Wk, const float* __restrict__ Wv,
    const int* __restrict__ x0i, const float* __restrict__ w1f,
    float* __restrict__ kt, float* __restrict__ vt, int n, int m)
{
    __shared__ float Wks[64][65];
    __shared__ float Wvs[64][65];
    __shared__ float kvs[4][64];
    __shared__ int   x0s[64];
    __shared__ float w1s[64];
    int nj = m >> 6;
    int jc = blockIdx.x % nj;
    int g  = (blockIdx.x / nj) & 7;
    int s  = blockIdx.x / (nj*8);
    int t  = threadIdx.x;
    int j0 = jc*64;
#pragma unroll
    for (int r = 0; r < 16; ++r) {
        int f = t + 256*r;
        int oc = f >> 6, ic = f & 63;
        Wks[oc][ic] = Wk[(size_t)(g*64+oc)*64 + ic];
        Wvs[oc][ic] = Wv[(size_t)(g*64+oc)*64 + ic];
    }
    if (t < 64) { x0s[t] = x0i[g*m + j0 + t]; w1s[t] = w1f[g*m + j0 + t]; }
    __syncthreads();
    const float* SRC = s ? x : px;   // kv_in = concat([prev, cur], axis=0)
    int jl = t >> 6, c = t & 63;
    for (int jq = 0; jq < 16; ++jq) {
        int jloc = jq*4 + jl;
        int i0 = x0s[jloc];
        float wgt = w1s[jloc];
        float v0 = (i0 >= 0   && i0   < n) ? SRC[(size_t)i0*DIMC + g*64 + c]     : 0.f;
        float v1 = (i0+1 >= 0 && i0+1 < n) ? SRC[(size_t)(i0+1)*DIMC + g*64 + c] : 0.f;
        kvs[jl][c] = v0*(1.0f - wgt) + v1*wgt;
        __syncthreads();
        float ka = 0.f, va = 0.f;
#pragma unroll 8
        for (int ic = 0; ic < 64; ++ic) {
            float kvv = kvs[jl][ic];           // broadcast
            ka += Wks[c][ic]*kvv;              // lane-varying row, pad 65 -> free
            va += Wvs[c][ic]*kvv;
        }
        size_t base = ((size_t)(s*8+g)*m + j0 + jloc)*64 + c;
        kt[base] = ka; vt[base] = va;          // coalesced
        __syncthreads();
    }
}

// ---------------- flash attention, fp32 vector ----------------
// lane = query, Q in regs; K/V rows broadcast-read from LDS; wave w owns d-range w*16
__global__ void k_attn(
    const float* __restrict__ q, const float* __restrict__ kt,
    const float* __restrict__ vt, float* __restrict__ ao, int n, int m)
{
    __shared__ float Ks[64][64];
    __shared__ float Vs[64][64];
    __shared__ float Ss[64][65];
    int nit = n >> 6;
    int it = blockIdx.x % nit;
    int h  = (blockIdx.x / nit) & 7;
    int s  = blockIdx.x / (nit*8);
    int t  = threadIdx.x;
    int lane = t & 63, w = t >> 6;
    int i0 = it*64;
    float Qown[64];
#pragma unroll
    for (int d = 0; d < 64; ++d)
        Qown[d] = q[(size_t)(h*64 + d)*n + i0 + lane] * 0.125f;  // 64^-0.5
    float mrun = -3.0e38f, lrun = 0.f;
    float oacc[16];
#pragma unroll
    for (int u = 0; u < 16; ++u) oacc[u] = 0.f;
    const float* kb = &kt[(size_t)(s*8+h)*m*64];
    const float* vb = &vt[(size_t)(s*8+h)*m*64];
    int ntile = m >> 6;
    for (int tk = 0; tk < ntile; ++tk) {
        __syncthreads();
#pragma unroll
        for (int r = 0; r < 4; ++r) {
            int f = t + 256*r;
            int jl = f >> 4, dq = f & 15;
            *(float4*)&Ks[jl][dq*4] = *(const float4*)&kb[(size_t)(tk*64 + jl)*64 + dq*4];
            *(float4*)&Vs[jl][dq*4] = *(const float4*)&vb[(size_t)(tk*64 + jl)*64 + dq*4];
        }
        __syncthreads();
        // sim: wave w computes j in [w*16, w*16+16) for all 64 queries (lanes)
#pragma unroll 2
        for (int jj = 0; jj < 16; ++jj) {
            int j = w*16 + jj;
            float s0=0.f, s1=0.f, s2=0.f, s3=0.f;
#pragma unroll
            for (int d4 = 0; d4 < 16; ++d4) {
                float4 kv4 = *(const float4*)&Ks[j][d4*4];   // broadcast
                s0 += Qown[d4*4+0]*kv4.x;
                s1 += Qown[d4*4+1]*kv4.y;
                s2 += Qown[d4*4+2]*kv4.z;
                s3 += Qown[d4*4+3]*kv4.w;
            }
            Ss[lane][j] = (s0+s1)+(s2+s3);
        }
        __syncthreads();
        // online softmax + PV: wave w owns d-range [w*16, w*16+16)
        float mt = -3.0e38f;
#pragma unroll 8
        for (int j = 0; j < 64; ++j) mt = fmaxf(mt, Ss[lane][j]);
        float mnew  = fmaxf(mrun, mt);
        float alpha = __expf(mrun - mnew);
        lrun *= alpha;
#pragma unroll
        for (int u = 0; u < 16; ++u) oacc[u] *= alpha;
#pragma unroll 4
        for (int j = 0; j < 64; ++j) {
            float p = __expf(Ss[lane][j] - mnew);
            lrun += p;
#pragma unroll
            for (int q4 = 0; q4 < 4; ++q4) {
                float4 vv = *(const float4*)&Vs[j][w*16 + q4*4];  // broadcast
                oacc[q4*4+0] += p*vv.x; oacc[q4*4+1] += p*vv.y;
                oacc[q4*4+2] += p*vv.z; oacc[q4*4+3] += p*vv.w;
            }
        }
        mrun = mnew;
    }
    __syncthreads();
    float inv = 1.0f / lrun;
#pragma unroll
    for (int u = 0; u < 16; ++u) Ss[lane][w*16 + u] = oacc[u]*inv;
    __syncthreads();
#pragma unroll
    for (int rr = 0; rr < 16; ++rr) {      // coalesced: lane = d
        int ir = w*16 + rr;
        ao[(size_t)(i0+ir)*1024 + s*512 + h*64 + lane] = Ss[ir][lane];
    }
}

// ---------------- Wo GEMM: out[i][d] = bo[d] + 0.5*sum_{c'=0..1023} ao[i][c']*WoT[c'&511][d] ----------------
__global__ __launch_bounds__(256) void k_out(
    const float* __restrict__ ao, const float* __restrict__ WoT,
    const float* __restrict__ bo, float* __restrict__ out, int n)
{
    __shared__ float As[64][65];
    __shared__ float Wsh[64][64];
    int i0 = blockIdx.x*64, d0 = blockIdx.y*64;
    int t = threadIdx.x;
    int lane = t & 63, w = t >> 6;    // lane = i, wave owns 16 dch
    float acc[16];
#pragma unroll
    for (int u = 0; u < 16; ++u) acc[u] = 0.f;
    for (int kc = 0; kc < 16; ++kc) {
        __syncthreads();
#pragma unroll
        for (int r = 0; r < 4; ++r) {
            int f = t + 256*r;
            int ir = f >> 4, kq = f & 15;
            float4 v = *(const float4*)&ao[(size_t)(i0+ir)*1024 + kc*64 + kq*4];
            As[ir][kq*4+0]=v.x; As[ir][kq*4+1]=v.y; As[ir][kq*4+2]=v.z; As[ir][kq*4+3]=v.w;
        }
#pragma unroll
        for (int r = 0; r < 4; ++r) {
            int f = t + 256*r;
            int kr = f >> 4, dq = f & 15;
            int c = (kc*64 + kr) & 511;
            *(float4*)&Wsh[kr][dq*4] = *(const float4*)&WoT[(size_t)c*DIMC + d0 + dq*4];
        }
        __syncthreads();
#pragma unroll 4
        for (int k = 0; k < 64; ++k) {
            float a = As[lane][k];
#pragma unroll
            for (int q4 = 0; q4 < 4; ++q4) {
                float4 wv = *(const float4*)&Wsh[k][w*16 + q4*4];   // broadcast
                acc[q4*4+0] += a*wv.x; acc[q4*4+1] += a*wv.y;
                acc[q4*4+2] += a*wv.z; acc[q4*4+3] += a*wv.w;
            }
        }
    }
    __syncthreads();
#pragma unroll
    for (int u = 0; u < 16; ++u) As[lane][w*16+u] = acc[u];
    __syncthreads();
#pragma unroll
    for (int rr = 0; rr < 16; ++rr) {      // coalesced: lane = dch
        int ir = w*16 + rr;
        out[(size_t)(i0+ir)*DIMC + d0 + lane] = bo[d0 + lane] + 0.5f*As[ir][lane];
    }
}

extern "C" void kernel_launch(void* const* d_in, const int* in_sizes, int n_in,
                              void* d_out, int out_size, void* d_ws, size_t ws_size,
                              hipStream_t stream)
{
    const float* x   = (const float*)d_in[0];
    const float* px  = (const float*)d_in[1];
    const float* Wq  = (const float*)d_in[2];
    const float* Wk  = (const float*)d_in[3];
    const float* Wv  = (const float*)d_in[4];
    const float* Wo  = (const float*)d_in[5];
    const float* bo  = (const float*)d_in[6];
    const float* Wdw = (const float*)d_in[7];
    const float* bdw = (const float*)d_in[8];
    const float* Wp  = (const float*)d_in[9];
    float* out = (float*)d_out;
    int n = in_sizes[0] / DIMC;     // 4096
    int m = n / 4;                  // 1024

    float* ws  = (float*)d_ws;
    float* q   = ws;                                  // 512*n
    int*   x0i = (int*)(ws + (size_t)512*n);          // 8*m
    float* w1f = ws + (size_t)512*n + 8*m;            // 8*m
    float* kt  = ws + (size_t)512*n + 16*m;           // 1024*m  [s][h][j][d]
    float* vt  = kt + (size_t)1024*m;                 // 1024*m
    float* ao  = vt + (size_t)1024*m;                 // n*1024  [i][s*512+h*64+d]
    float* WoT = ao + (size_t)n*1024;                 // 512*512

    k_wot  <<<dim3(16,16),      256, 0, stream>>>(Wo, WoT);
    k_qconv<<<dim3(8, n/64),    256, 0, stream>>>(x, px, Wq, q, n);
    k_off  <<<(NG*m + 255)/256, 256, 0, stream>>>(q, Wdw, bdw, Wp, x0i, w1f, n, m);
    k_kv   <<<2*8*(m/64),       256, 0, stream>>>(x, px, Wk, Wv, x0i, w1f, kt, vt, n, m);
    k_attn <<<2*8*(n/64),       256, 0, stream>>>(q, kt, vt, ao, n, m);
    k_out  <<<dim3(n/64, 8),    256, 0, stream>>>(ao, WoT, bo, out, n);
}

// Round 2
// 347.645 us; speedup vs baseline: 6.1921x; 6.1921x over previous
//
#include <hip/hip_runtime.h>
#include <math.h>

#define DIMC 512
#define NG 8

typedef _Float16 half8 __attribute__((ext_vector_type(8)));
typedef float f32x4 __attribute__((ext_vector_type(4)));

// ---------------- Wo (512x512) -> WoT transpose ----------------
__global__ __launch_bounds__(256) void k_wot(const float* __restrict__ Wo, float* __restrict__ WoT) {
    __shared__ float tile[32][33];
    int bx = blockIdx.x, by = blockIdx.y;
    int tx = threadIdx.x & 31, ty = threadIdx.x >> 5;  // 32x8
#pragma unroll
    for (int r = 0; r < 4; ++r)
        tile[ty + r*8][tx] = Wo[(size_t)(by*32 + ty + r*8)*DIMC + bx*32 + tx];
    __syncthreads();
#pragma unroll
    for (int r = 0; r < 4; ++r)
        WoT[(size_t)(bx*32 + ty + r*8)*DIMC + by*32 + tx] = tile[tx][ty + r*8];
}

// ---------------- q = grouped 1x1 conv over concat[prev_x, x] ----------------
// q fp32 channel-major (for offset net) + qh f16 [h][i][d] pre-scaled by 0.125 (for attention)
__global__ __launch_bounds__(256) void k_qconv(
    const float* __restrict__ x, const float* __restrict__ px,
    const float* __restrict__ Wq, float* __restrict__ q, _Float16* __restrict__ qh, int n)
{
    __shared__ float Xs[64][129];
    __shared__ float Wt[128][68];
    int g  = blockIdx.x;            // 0..7 == head
    int i0 = blockIdx.y * 64;
    int t  = threadIdx.x;
    const float* SRC = (g < 4) ? px : x;   // concat puts prev first
    int cbase = (g & 3) * 128;
#pragma unroll
    for (int r = 0; r < 8; ++r) {
        int f = t + 256*r;
        int i = f >> 5, kq = f & 31;
        float4 v = *(const float4*)&SRC[(size_t)(i0+i)*DIMC + cbase + kq*4];
        Xs[i][kq*4+0] = v.x; Xs[i][kq*4+1] = v.y; Xs[i][kq*4+2] = v.z; Xs[i][kq*4+3] = v.w;
    }
#pragma unroll
    for (int r = 0; r < 32; ++r) {
        int f = t + 256*r;
        int oc = f & 63, kk = f >> 6;
        Wt[kk][oc] = Wq[(size_t)(g*64+oc)*128 + kk];
    }
    __syncthreads();
    int lane = t & 63, w = t >> 6;         // lane = i, wave owns 16 oc
    float acc[16];
#pragma unroll
    for (int u = 0; u < 16; ++u) acc[u] = 0.f;
#pragma unroll 4
    for (int k = 0; k < 128; ++k) {
        float xv = Xs[lane][k];
#pragma unroll
        for (int q4 = 0; q4 < 4; ++q4) {
            float4 wv = *(const float4*)&Wt[k][w*16 + q4*4];   // broadcast
            acc[q4*4+0] += xv*wv.x; acc[q4*4+1] += xv*wv.y;
            acc[q4*4+2] += xv*wv.z; acc[q4*4+3] += xv*wv.w;
        }
    }
#pragma unroll
    for (int u = 0; u < 16; ++u)           // coalesced over lane=i
        q[(size_t)(g*64 + w*16 + u)*n + i0 + lane] = acc[u];
    // transpose through LDS -> qh f16 [h][i][d], scaled by 64^-0.5
    __syncthreads();
#pragma unroll
    for (int u = 0; u < 16; ++u) Xs[lane][w*16 + u] = acc[u];
    __syncthreads();
    {
        int i = t >> 2, qd = t & 3;
        union { _Float16 h[16]; uint4 v[2]; } pk;
#pragma unroll
        for (int v = 0; v < 16; ++v) pk.h[v] = (_Float16)(Xs[i][qd*16 + v] * 0.125f);
        uint4* dst = (uint4*)&qh[((size_t)g*n + i0 + i)*64 + qd*16];
        dst[0] = pk.v[0]; dst[1] = pk.v[1];
    }
}

// ---------------- offset net: depthwise conv s4 + GELU + 1x1 + tanh -> sample pos ----------------
__global__ __launch_bounds__(256) void k_off(
    const float* __restrict__ q, const float* __restrict__ Wdw,
    const float* __restrict__ bdw, const float* __restrict__ Wp,
    int* __restrict__ x0i, float* __restrict__ w1f, int n, int m)
{
    int idx = blockIdx.x*256 + threadIdx.x;
    if (idx >= NG*m) return;
    int gg = idx / m, j = idx - gg*m;
    float off = 0.f;
    for (int c = 0; c < 64; ++c) {
        float h = bdw[c];
        const float* qrow = &q[(size_t)(gg*64 + c)*n];
#pragma unroll
        for (int tt = 0; tt < 6; ++tt) {
            int p = 4*j - 1 + tt;                 // stride 4, pad 1
            if (p >= 0 && p < n) h += Wdw[c*6 + tt] * qrow[p];
        }
        float ge = 0.5f * h * (1.0f + erff(h * 0.70710678118654752f));  // exact gelu
        off += Wp[c] * ge;
    }
    off = tanhf(off) * 4.0f;
    float vg  = 2.0f * ((float)j + off) / (float)(m - 1) - 1.0f;
    float pos = ((vg + 1.0f) * (float)n - 1.0f) * 0.5f;
    float x0  = floorf(pos);
    x0i[idx] = (int)x0;
    w1f[idx] = pos - x0;
}

// ---------------- grid-sample + k/v grouped 1x1 convs ----------------
// kt16 f16 [s][h][j][d]; vt16 f16 TRANSPOSED [s][h][d][j] (B-fragment friendly)
__global__ __launch_bounds__(256) void k_kv(
    const float* __restrict__ x, const float* __restrict__ px,
    const float* __restrict__ Wk, const float* __restrict__ Wv,
    const int* __restrict__ x0i, const float* __restrict__ w1f,
    _Float16* __restrict__ kt16, _Float16* __restrict__ vt16, int n, int m)
{
    __shared__ float Wks[64][65];
    __shared__ float Wvs[64][65];
    __shared__ float kvs[4][64];
    __shared__ int   x0s[64];
    __shared__ float w1s[64];
    int nj = m >> 6;
    int jc = blockIdx.x % nj;
    int g  = (blockIdx.x / nj) & 7;
    int s  = blockIdx.x / (nj*8);
    int t  = threadIdx.x;
    int j0 = jc*64;
#pragma unroll
    for (int r = 0; r < 16; ++r) {
        int f = t + 256*r;
        int oc = f >> 6, ic = f & 63;
        Wks[oc][ic] = Wk[(size_t)(g*64+oc)*64 + ic];
        Wvs[oc][ic] = Wv[(size_t)(g*64+oc)*64 + ic];
    }
    if (t < 64) { x0s[t] = x0i[g*m + j0 + t]; w1s[t] = w1f[g*m + j0 + t]; }
    __syncthreads();
    const float* SRC = s ? x : px;   // kv_in = concat([prev, cur], axis=0)
    int jl = t >> 6, c = t & 63;
    for (int jq = 0; jq < 16; ++jq) {
        int jloc = jq*4 + jl;
        int i0 = x0s[jloc];
        float wgt = w1s[jloc];
        float v0 = (i0 >= 0   && i0   < n) ? SRC[(size_t)i0*DIMC + g*64 + c]     : 0.f;
        float v1 = (i0+1 >= 0 && i0+1 < n) ? SRC[(size_t)(i0+1)*DIMC + g*64 + c] : 0.f;
        kvs[jl][c] = v0*(1.0f - wgt) + v1*wgt;
        __syncthreads();
        float ka = 0.f, va = 0.f;
#pragma unroll 8
        for (int ic = 0; ic < 64; ++ic) {
            float kvv = kvs[jl][ic];           // broadcast
            ka += Wks[c][ic]*kvv;
            va += Wvs[c][ic]*kvv;
        }
        kt16[((size_t)(s*8+g)*m + j0 + jloc)*64 + c]   = (_Float16)ka;  // coalesced
        vt16[((size_t)(s*8+g)*64 + c)*m + j0 + jloc]   = (_Float16)va;  // strided, tiny total
        __syncthreads();
    }
}

// ---------------- flash attention, f16 MFMA ----------------
// block = one (s,h), 64-query tile. Wave w owns 16-query strip.
// A/B frag layout (gfx950 16x16x32): A[m=lane&15][k=(lane>>4)*8+j], B[k=(lane>>4)*8+j][n=lane&15]
// C/D: row=(lane>>4)*4+r, col=lane&15
__global__ __launch_bounds__(256, 2) void k_attn(
    const _Float16* __restrict__ qh, const _Float16* __restrict__ kt16,
    const _Float16* __restrict__ vt16, float* __restrict__ ao, int n, int m)
{
    __shared__ _Float16 Qs[64*72];   // [i][d] pad 72
    __shared__ _Float16 Ks[64*72];   // [j][d]
    __shared__ _Float16 Vs[64*72];   // [d][j]  (V transposed)
    __shared__ _Float16 Ps[64*72];   // [i][j]  per-wave-private 16-row strips
    int nit = n >> 6;
    int it = blockIdx.x % nit;
    int h  = (blockIdx.x / nit) & 7;
    int s  = blockIdx.x / (nit*8);
    int t  = threadIdx.x;
    int lane = t & 63, w = t >> 6;
    int l15 = lane & 15, quad = lane >> 4;
    int i0 = it*64;

    // stage Q tile once: [64][64] f16
    const _Float16* qb = &qh[((size_t)h*n + i0)*64];
#pragma unroll
    for (int r = 0; r < 2; ++r) {
        int c = t + 256*r;               // 512 chunks of 8 f16
        int i = c >> 3, oct = c & 7;
        *(uint4*)&Qs[i*72 + oct*8] = *(const uint4*)&qb[i*64 + oct*8];
    }

    const _Float16* kb = &kt16[(size_t)(s*8+h)*m*64];   // [j][d]
    const _Float16* vb = &vt16[(size_t)(s*8+h)*64*m];   // [d][j]

    float mrun[4], lrun[4];
#pragma unroll
    for (int r = 0; r < 4; ++r) { mrun[r] = -3.0e38f; lrun[r] = 0.f; }
    f32x4 oacc[4];
#pragma unroll
    for (int dt = 0; dt < 4; ++dt) oacc[dt] = (f32x4){0.f,0.f,0.f,0.f};

    int ntile = m >> 6;
    for (int tk = 0; tk < ntile; ++tk) {
        __syncthreads();   // protect Ks/Vs from prior tile readers
#pragma unroll
        for (int r = 0; r < 2; ++r) {
            int c = t + 256*r;
            int row = c >> 3, oct = c & 7;
            *(uint4*)&Ks[row*72 + oct*8] = *(const uint4*)&kb[(size_t)(tk*64 + row)*64 + oct*8];
            *(uint4*)&Vs[row*72 + oct*8] = *(const uint4*)&vb[(size_t)row*m + tk*64 + oct*8];
        }
        __syncthreads();

        // S = Q K^T : wave strip 16 i x 64 j
        f32x4 accs[4];
#pragma unroll
        for (int jt = 0; jt < 4; ++jt) accs[jt] = (f32x4){0.f,0.f,0.f,0.f};
#pragma unroll
        for (int ks = 0; ks < 2; ++ks) {
            half8 aq = *(const half8*)&Qs[(w*16 + l15)*72 + ks*32 + quad*8];
#pragma unroll
            for (int jt = 0; jt < 4; ++jt) {
                half8 bk = *(const half8*)&Ks[(jt*16 + l15)*72 + ks*32 + quad*8];
                accs[jt] = __builtin_amdgcn_mfma_f32_16x16x32_f16(aq, bk, accs[jt], 0, 0, 0);
            }
        }

        // online softmax over the wave's 16 rows (row r lives on 16 lanes of this quad-group)
        float mt[4], rs[4];
#pragma unroll
        for (int r = 0; r < 4; ++r) {
            float v = accs[0][r];
            v = fmaxf(v, accs[1][r]); v = fmaxf(v, accs[2][r]); v = fmaxf(v, accs[3][r]);
            mt[r] = v;
        }
#pragma unroll
        for (int msk = 1; msk <= 8; msk <<= 1)
#pragma unroll
            for (int r = 0; r < 4; ++r) mt[r] = fmaxf(mt[r], __shfl_xor(mt[r], msk, 64));
#pragma unroll
        for (int r = 0; r < 4; ++r) {
            float mnew = fmaxf(mrun[r], mt[r]);
            float al   = __expf(mrun[r] - mnew);
            mrun[r] = mnew;
            lrun[r] *= al;
            rs[r] = 0.f;
#pragma unroll
            for (int jt = 0; jt < 4; ++jt) {
                float p = __expf(accs[jt][r] - mnew);
                accs[jt][r] = p;
                rs[r] += p;
            }
#pragma unroll
            for (int dt = 0; dt < 4; ++dt) oacc[dt][r] *= al;
        }
#pragma unroll
        for (int msk = 1; msk <= 8; msk <<= 1)
#pragma unroll
            for (int r = 0; r < 4; ++r) rs[r] += __shfl_xor(rs[r], msk, 64);
#pragma unroll
        for (int r = 0; r < 4; ++r) lrun[r] += rs[r];

        // P (C layout) -> LDS f16 (wave-private strip, no barrier needed)
#pragma unroll
        for (int jt = 0; jt < 4; ++jt)
#pragma unroll
            for (int r = 0; r < 4; ++r)
                Ps[(w*16 + quad*4 + r)*72 + jt*16 + l15] = (_Float16)accs[jt][r];

        // O += P V  (A = P from LDS in A-layout, B = Vt)
#pragma unroll
        for (int ks = 0; ks < 2; ++ks) {
            half8 ap = *(const half8*)&Ps[(w*16 + l15)*72 + ks*32 + quad*8];
#pragma unroll
            for (int dt = 0; dt < 4; ++dt) {
                half8 bv = *(const half8*)&Vs[(dt*16 + l15)*72 + ks*32 + quad*8];
                oacc[dt] = __builtin_amdgcn_mfma_f32_16x16x32_f16(ap, bv, oacc[dt], 0, 0, 0);
            }
        }
    }

    // epilogue: normalize, store (C layout: i = w*16 + quad*4 + r, d = dt*16 + l15)
    float inv[4];
#pragma unroll
    for (int r = 0; r < 4; ++r) inv[r] = 1.0f / lrun[r];
#pragma unroll
    for (int dt = 0; dt < 4; ++dt)
#pragma unroll
        for (int r = 0; r < 4; ++r)
            ao[(size_t)(i0 + w*16 + quad*4 + r)*1024 + s*512 + h*64 + dt*16 + l15]
                = oacc[dt][r] * inv[r];
}

// ---------------- Wo GEMM: out[i][d] = bo[d] + 0.5*sum_{c'} ao[i][c']*WoT[c'&511][d] ----------------
__global__ __launch_bounds__(256) void k_out(
    const float* __restrict__ ao, const float* __restrict__ WoT,
    const float* __restrict__ bo, float* __restrict__ out, int n)
{
    __shared__ float As[64][65];
    __shared__ float Wsh[64][64];
    int i0 = blockIdx.x*64, d0 = blockIdx.y*64;
    int t = threadIdx.x;
    int lane = t & 63, w = t >> 6;
    float acc[16];
#pragma unroll
    for (int u = 0; u < 16; ++u) acc[u] = 0.f;
    for (int kc = 0; kc < 16; ++kc) {
        __syncthreads();
#pragma unroll
        for (int r = 0; r < 4; ++r) {
            int f = t + 256*r;
            int ir = f >> 4, kq = f & 15;
            float4 v = *(const float4*)&ao[(size_t)(i0+ir)*1024 + kc*64 + kq*4];
            As[ir][kq*4+0]=v.x; As[ir][kq*4+1]=v.y; As[ir][kq*4+2]=v.z; As[ir][kq*4+3]=v.w;
        }
#pragma unroll
        for (int r = 0; r < 4; ++r) {
            int f = t + 256*r;
            int kr = f >> 4, dq = f & 15;
            int c = (kc*64 + kr) & 511;
            *(float4*)&Wsh[kr][dq*4] = *(const float4*)&WoT[(size_t)c*DIMC + d0 + dq*4];
        }
        __syncthreads();
#pragma unroll 4
        for (int k = 0; k < 64; ++k) {
            float a = As[lane][k];
#pragma unroll
            for (int q4 = 0; q4 < 4; ++q4) {
                float4 wv = *(const float4*)&Wsh[k][w*16 + q4*4];   // broadcast
                acc[q4*4+0] += a*wv.x; acc[q4*4+1] += a*wv.y;
                acc[q4*4+2] += a*wv.z; acc[q4*4+3] += a*wv.w;
            }
        }
    }
    __syncthreads();
#pragma unroll
    for (int u = 0; u < 16; ++u) As[lane][w*16+u] = acc[u];
    __syncthreads();
#pragma unroll
    for (int rr = 0; rr < 16; ++rr) {
        int ir = w*16 + rr;
        out[(size_t)(i0+ir)*DIMC + d0 + lane] = bo[d0 + lane] + 0.5f*As[ir][lane];
    }
}

extern "C" void kernel_launch(void* const* d_in, const int* in_sizes, int n_in,
                              void* d_out, int out_size, void* d_ws, size_t ws_size,
                              hipStream_t stream)
{
    const float* x   = (const float*)d_in[0];
    const float* px  = (const float*)d_in[1];
    const float* Wq  = (const float*)d_in[2];
    const float* Wk  = (const float*)d_in[3];
    const float* Wv  = (const float*)d_in[4];
    const float* Wo  = (const float*)d_in[5];
    const float* bo  = (const float*)d_in[6];
    const float* Wdw = (const float*)d_in[7];
    const float* bdw = (const float*)d_in[8];
    const float* Wp  = (const float*)d_in[9];
    float* out = (float*)d_out;
    int n = in_sizes[0] / DIMC;     // 4096
    int m = n / 4;                  // 1024

    float* ws  = (float*)d_ws;
    float* q    = ws;                                 // 512*n f32
    float* WoT  = q + (size_t)512*n;                  // 512*512 f32
    float* ao   = WoT + (size_t)512*512;              // n*1024 f32
    int*   x0i  = (int*)(ao + (size_t)n*1024);        // 8*m
    float* w1f  = (float*)(x0i + 8*m);                // 8*m
    _Float16* qhf  = (_Float16*)(w1f + 8*m);          // 8*n*64 f16  [h][i][d]
    _Float16* kt16 = qhf + (size_t)8*n*64;            // 2*8*m*64 f16 [s][h][j][d]
    _Float16* vt16 = kt16 + (size_t)16*m*64;          // 2*8*m*64 f16 [s][h][d][j]

    k_wot  <<<dim3(16,16),      256, 0, stream>>>(Wo, WoT);
    k_qconv<<<dim3(8, n/64),    256, 0, stream>>>(x, px, Wq, q, qhf, n);
    k_off  <<<(NG*m + 255)/256, 256, 0, stream>>>(q, Wdw, bdw, Wp, x0i, w1f, n, m);
    k_kv   <<<2*8*(m/64),       256, 0, stream>>>(x, px, Wk, Wv, x0i, w1f, kt16, vt16, n, m);
    k_attn <<<2*8*(n/64),       256, 0, stream>>>(qhf, kt16, vt16, ao, n, m);
    k_out  <<<dim3(n/64, 8),    256, 0, stream>>>(ao, WoT, bo, out, n);
}

// Round 3
// 284.197 us; speedup vs baseline: 7.5746x; 1.2233x over previous
//
#include <hip/hip_runtime.h>
#include <math.h>

#define DIMC 512
#define NG 8

typedef _Float16 half8 __attribute__((ext_vector_type(8)));
typedef float f32x4 __attribute__((ext_vector_type(4)));

// ---------------- Wo f32 -> f16 cast (native [d][c] layout == MFMA B layout) ----------------
__global__ __launch_bounds__(256) void k_wcvt(const float* __restrict__ Wo, _Float16* __restrict__ Woh) {
    int idx = (blockIdx.x*256 + threadIdx.x) * 8;   // 128 blocks * 256 t * 8 = 262144
    float4 a = *(const float4*)&Wo[idx];
    float4 b = *(const float4*)&Wo[idx+4];
    union { _Float16 h[8]; uint4 v; } pk;
    pk.h[0]=(_Float16)a.x; pk.h[1]=(_Float16)a.y; pk.h[2]=(_Float16)a.z; pk.h[3]=(_Float16)a.w;
    pk.h[4]=(_Float16)b.x; pk.h[5]=(_Float16)b.y; pk.h[6]=(_Float16)b.z; pk.h[7]=(_Float16)b.w;
    *(uint4*)&Woh[idx] = pk.v;
}

// ---------------- q = grouped 1x1 conv over concat[prev_x, x] ----------------
// q fp32 channel-major (for offset net) + qh f16 [h][i][d] pre-scaled by 0.125 (for attention)
__global__ __launch_bounds__(256) void k_qconv(
    const float* __restrict__ x, const float* __restrict__ px,
    const float* __restrict__ Wq, float* __restrict__ q, _Float16* __restrict__ qh, int n)
{
    __shared__ float Xs[64][129];
    __shared__ float Wt[128][68];
    int g  = blockIdx.x;            // 0..7 == head
    int i0 = blockIdx.y * 64;
    int t  = threadIdx.x;
    const float* SRC = (g < 4) ? px : x;   // concat puts prev first
    int cbase = (g & 3) * 128;
#pragma unroll
    for (int r = 0; r < 8; ++r) {
        int f = t + 256*r;
        int i = f >> 5, kq = f & 31;
        float4 v = *(const float4*)&SRC[(size_t)(i0+i)*DIMC + cbase + kq*4];
        Xs[i][kq*4+0] = v.x; Xs[i][kq*4+1] = v.y; Xs[i][kq*4+2] = v.z; Xs[i][kq*4+3] = v.w;
    }
#pragma unroll
    for (int r = 0; r < 32; ++r) {
        int f = t + 256*r;
        int oc = f & 63, kk = f >> 6;
        Wt[kk][oc] = Wq[(size_t)(g*64+oc)*128 + kk];
    }
    __syncthreads();
    int lane = t & 63, w = t >> 6;         // lane = i, wave owns 16 oc
    float acc[16];
#pragma unroll
    for (int u = 0; u < 16; ++u) acc[u] = 0.f;
#pragma unroll 4
    for (int k = 0; k < 128; ++k) {
        float xv = Xs[lane][k];
#pragma unroll
        for (int q4 = 0; q4 < 4; ++q4) {
            float4 wv = *(const float4*)&Wt[k][w*16 + q4*4];   // broadcast
            acc[q4*4+0] += xv*wv.x; acc[q4*4+1] += xv*wv.y;
            acc[q4*4+2] += xv*wv.z; acc[q4*4+3] += xv*wv.w;
        }
    }
#pragma unroll
    for (int u = 0; u < 16; ++u)           // coalesced over lane=i
        q[(size_t)(g*64 + w*16 + u)*n + i0 + lane] = acc[u];
    // transpose through LDS -> qh f16 [h][i][d], scaled by 64^-0.5
    __syncthreads();
#pragma unroll
    for (int u = 0; u < 16; ++u) Xs[lane][w*16 + u] = acc[u];
    __syncthreads();
    {
        int i = t >> 2, qd = t & 3;
        union { _Float16 h[16]; uint4 v[2]; } pk;
#pragma unroll
        for (int v = 0; v < 16; ++v) pk.h[v] = (_Float16)(Xs[i][qd*16 + v] * 0.125f);
        uint4* dst = (uint4*)&qh[((size_t)g*n + i0 + i)*64 + qd*16];
        dst[0] = pk.v[0]; dst[1] = pk.v[1];
    }
}

// ---------------- offset net: depthwise conv s4 + GELU + 1x1 + tanh -> sample pos ----------------
__global__ __launch_bounds__(256) void k_off(
    const float* __restrict__ q, const float* __restrict__ Wdw,
    const float* __restrict__ bdw, const float* __restrict__ Wp,
    int* __restrict__ x0i, float* __restrict__ w1f, int n, int m)
{
    int idx = blockIdx.x*256 + threadIdx.x;
    if (idx >= NG*m) return;
    int gg = idx / m, j = idx - gg*m;
    float off = 0.f;
    for (int c = 0; c < 64; ++c) {
        float h = bdw[c];
        const float* qrow = &q[(size_t)(gg*64 + c)*n];
#pragma unroll
        for (int tt = 0; tt < 6; ++tt) {
            int p = 4*j - 1 + tt;                 // stride 4, pad 1
            if (p >= 0 && p < n) h += Wdw[c*6 + tt] * qrow[p];
        }
        float ge = 0.5f * h * (1.0f + erff(h * 0.70710678118654752f));  // exact gelu
        off += Wp[c] * ge;
    }
    off = tanhf(off) * 4.0f;
    float vg  = 2.0f * ((float)j + off) / (float)(m - 1) - 1.0f;
    float pos = ((vg + 1.0f) * (float)n - 1.0f) * 0.5f;
    float x0  = floorf(pos);
    x0i[idx] = (int)x0;
    w1f[idx] = pos - x0;
}

// ---------------- grid-sample + k/v grouped 1x1 convs ----------------
// kt16 f16 [s][h][j][d]; vt16 f16 TRANSPOSED [s][h][d][j] (B-fragment friendly)
__global__ __launch_bounds__(256) void k_kv(
    const float* __restrict__ x, const float* __restrict__ px,
    const float* __restrict__ Wk, const float* __restrict__ Wv,
    const int* __restrict__ x0i, const float* __restrict__ w1f,
    _Float16* __restrict__ kt16, _Float16* __restrict__ vt16, int n, int m)
{
    __shared__ float Wks[64][65];
    __shared__ float Wvs[64][65];
    __shared__ float kvs[4][64];
    __shared__ int   x0s[64];
    __shared__ float w1s[64];
    int nj = m >> 6;
    int jc = blockIdx.x % nj;
    int g  = (blockIdx.x / nj) & 7;
    int s  = blockIdx.x / (nj*8);
    int t  = threadIdx.x;
    int j0 = jc*64;
#pragma unroll
    for (int r = 0; r < 16; ++r) {
        int f = t + 256*r;
        int oc = f >> 6, ic = f & 63;
        Wks[oc][ic] = Wk[(size_t)(g*64+oc)*64 + ic];
        Wvs[oc][ic] = Wv[(size_t)(g*64+oc)*64 + ic];
    }
    if (t < 64) { x0s[t] = x0i[g*m + j0 + t]; w1s[t] = w1f[g*m + j0 + t]; }
    __syncthreads();
    const float* SRC = s ? x : px;   // kv_in = concat([prev, cur], axis=0)
    int jl = t >> 6, c = t & 63;
    for (int jq = 0; jq < 16; ++jq) {
        int jloc = jq*4 + jl;
        int i0 = x0s[jloc];
        float wgt = w1s[jloc];
        float v0 = (i0 >= 0   && i0   < n) ? SRC[(size_t)i0*DIMC + g*64 + c]     : 0.f;
        float v1 = (i0+1 >= 0 && i0+1 < n) ? SRC[(size_t)(i0+1)*DIMC + g*64 + c] : 0.f;
        kvs[jl][c] = v0*(1.0f - wgt) + v1*wgt;
        __syncthreads();
        float ka = 0.f, va = 0.f;
#pragma unroll 8
        for (int ic = 0; ic < 64; ++ic) {
            float kvv = kvs[jl][ic];           // broadcast
            ka += Wks[c][ic]*kvv;
            va += Wvs[c][ic]*kvv;
        }
        kt16[((size_t)(s*8+g)*m + j0 + jloc)*64 + c]   = (_Float16)ka;  // coalesced
        vt16[((size_t)(s*8+g)*64 + c)*m + j0 + jloc]   = (_Float16)va;  // strided, tiny total
        __syncthreads();
    }
}

// ---------------- flash attention, f16 MFMA ----------------
__global__ __launch_bounds__(256, 2) void k_attn(
    const _Float16* __restrict__ qh, const _Float16* __restrict__ kt16,
    const _Float16* __restrict__ vt16, _Float16* __restrict__ aoh, int n, int m)
{
    __shared__ _Float16 Qs[64*72];   // [i][d] pad 72
    __shared__ _Float16 Ks[64*72];   // [j][d]
    __shared__ _Float16 Vs[64*72];   // [d][j]  (V transposed)
    __shared__ _Float16 Ps[64*72];   // [i][j]  per-wave-private 16-row strips
    int nit = n >> 6;
    int it = blockIdx.x % nit;
    int h  = (blockIdx.x / nit) & 7;
    int s  = blockIdx.x / (nit*8);
    int t  = threadIdx.x;
    int lane = t & 63, w = t >> 6;
    int l15 = lane & 15, quad = lane >> 4;
    int i0 = it*64;

    const _Float16* qb = &qh[((size_t)h*n + i0)*64];
#pragma unroll
    for (int r = 0; r < 2; ++r) {
        int c = t + 256*r;
        int i = c >> 3, oct = c & 7;
        *(uint4*)&Qs[i*72 + oct*8] = *(const uint4*)&qb[i*64 + oct*8];
    }

    const _Float16* kb = &kt16[(size_t)(s*8+h)*m*64];   // [j][d]
    const _Float16* vb = &vt16[(size_t)(s*8+h)*64*m];   // [d][j]

    float mrun[4], lrun[4];
#pragma unroll
    for (int r = 0; r < 4; ++r) { mrun[r] = -3.0e38f; lrun[r] = 0.f; }
    f32x4 oacc[4];
#pragma unroll
    for (int dt = 0; dt < 4; ++dt) oacc[dt] = (f32x4){0.f,0.f,0.f,0.f};

    int ntile = m >> 6;
    for (int tk = 0; tk < ntile; ++tk) {
        __syncthreads();
#pragma unroll
        for (int r = 0; r < 2; ++r) {
            int c = t + 256*r;
            int row = c >> 3, oct = c & 7;
            *(uint4*)&Ks[row*72 + oct*8] = *(const uint4*)&kb[(size_t)(tk*64 + row)*64 + oct*8];
            *(uint4*)&Vs[row*72 + oct*8] = *(const uint4*)&vb[(size_t)row*m + tk*64 + oct*8];
        }
        __syncthreads();

        f32x4 accs[4];
#pragma unroll
        for (int jt = 0; jt < 4; ++jt) accs[jt] = (f32x4){0.f,0.f,0.f,0.f};
#pragma unroll
        for (int ks = 0; ks < 2; ++ks) {
            half8 aq = *(const half8*)&Qs[(w*16 + l15)*72 + ks*32 + quad*8];
#pragma unroll
            for (int jt = 0; jt < 4; ++jt) {
                half8 bk = *(const half8*)&Ks[(jt*16 + l15)*72 + ks*32 + quad*8];
                accs[jt] = __builtin_amdgcn_mfma_f32_16x16x32_f16(aq, bk, accs[jt], 0, 0, 0);
            }
        }

        float mt[4], rs[4];
#pragma unroll
        for (int r = 0; r < 4; ++r) {
            float v = accs[0][r];
            v = fmaxf(v, accs[1][r]); v = fmaxf(v, accs[2][r]); v = fmaxf(v, accs[3][r]);
            mt[r] = v;
        }
#pragma unroll
        for (int msk = 1; msk <= 8; msk <<= 1)
#pragma unroll
            for (int r = 0; r < 4; ++r) mt[r] = fmaxf(mt[r], __shfl_xor(mt[r], msk, 64));
#pragma unroll
        for (int r = 0; r < 4; ++r) {
            float mnew = fmaxf(mrun[r], mt[r]);
            float al   = __expf(mrun[r] - mnew);
            mrun[r] = mnew;
            lrun[r] *= al;
            rs[r] = 0.f;
#pragma unroll
            for (int jt = 0; jt < 4; ++jt) {
                float p = __expf(accs[jt][r] - mnew);
                accs[jt][r] = p;
                rs[r] += p;
            }
#pragma unroll
            for (int dt = 0; dt < 4; ++dt) oacc[dt][r] *= al;
        }
#pragma unroll
        for (int msk = 1; msk <= 8; msk <<= 1)
#pragma unroll
            for (int r = 0; r < 4; ++r) rs[r] += __shfl_xor(rs[r], msk, 64);
#pragma unroll
        for (int r = 0; r < 4; ++r) lrun[r] += rs[r];

#pragma unroll
        for (int jt = 0; jt < 4; ++jt)
#pragma unroll
            for (int r = 0; r < 4; ++r)
                Ps[(w*16 + quad*4 + r)*72 + jt*16 + l15] = (_Float16)accs[jt][r];

#pragma unroll
        for (int ks = 0; ks < 2; ++ks) {
            half8 ap = *(const half8*)&Ps[(w*16 + l15)*72 + ks*32 + quad*8];
#pragma unroll
            for (int dt = 0; dt < 4; ++dt) {
                half8 bv = *(const half8*)&Vs[(dt*16 + l15)*72 + ks*32 + quad*8];
                oacc[dt] = __builtin_amdgcn_mfma_f32_16x16x32_f16(ap, bv, oacc[dt], 0, 0, 0);
            }
        }
    }

    // epilogue: normalize, store f16 (C layout: i = w*16+quad*4+r, d = dt*16+l15)
    float inv[4];
#pragma unroll
    for (int r = 0; r < 4; ++r) inv[r] = 1.0f / lrun[r];
#pragma unroll
    for (int dt = 0; dt < 4; ++dt)
#pragma unroll
        for (int r = 0; r < 4; ++r)
            aoh[(size_t)(i0 + w*16 + quad*4 + r)*1024 + s*512 + h*64 + dt*16 + l15]
                = (_Float16)(oacc[dt][r] * inv[r]);
}

// ---------------- Wo GEMM, f16 MFMA: out[i][d] = bo[d] + 0.5*sum_{c'} aoh[i][c']*Woh[d][c'&511] ----------------
__global__ __launch_bounds__(256) void k_out(
    const _Float16* __restrict__ aoh, const _Float16* __restrict__ Woh,
    const float* __restrict__ bo, float* __restrict__ out, int n)
{
    __shared__ _Float16 As[64*72];   // [i][k]
    __shared__ _Float16 Ws[64*72];   // [d][k]
    int i0 = blockIdx.x*64, d0 = blockIdx.y*64;
    int t = threadIdx.x;
    int lane = t & 63, w = t >> 6;
    int l15 = lane & 15, quad = lane >> 4;
    f32x4 oacc[4];
#pragma unroll
    for (int dt = 0; dt < 4; ++dt) oacc[dt] = (f32x4){0.f,0.f,0.f,0.f};

    for (int kc = 0; kc < 16; ++kc) {        // K' = 1024 in chunks of 64
        int cbase = (kc & 7) * 64;           // c = c' & 511 (chunks never straddle)
        __syncthreads();
#pragma unroll
        for (int r = 0; r < 2; ++r) {
            int c = t + 256*r;
            int row = c >> 3, oct = c & 7;
            *(uint4*)&As[row*72 + oct*8] = *(const uint4*)&aoh[(size_t)(i0+row)*1024 + kc*64 + oct*8];
            *(uint4*)&Ws[row*72 + oct*8] = *(const uint4*)&Woh[(size_t)(d0+row)*DIMC + cbase + oct*8];
        }
        __syncthreads();
#pragma unroll
        for (int ks = 0; ks < 2; ++ks) {
            half8 aq = *(const half8*)&As[(w*16 + l15)*72 + ks*32 + quad*8];
#pragma unroll
            for (int dt = 0; dt < 4; ++dt) {
                half8 bw = *(const half8*)&Ws[(dt*16 + l15)*72 + ks*32 + quad*8];
                oacc[dt] = __builtin_amdgcn_mfma_f32_16x16x32_f16(aq, bw, oacc[dt], 0, 0, 0);
            }
        }
    }
    // C layout: i = w*16+quad*4+r, d = dt*16+l15
#pragma unroll
    for (int dt = 0; dt < 4; ++dt) {
        float bias = bo[d0 + dt*16 + l15];
#pragma unroll
        for (int r = 0; r < 4; ++r)
            out[(size_t)(i0 + w*16 + quad*4 + r)*DIMC + d0 + dt*16 + l15]
                = bias + 0.5f*oacc[dt][r];
    }
}

extern "C" void kernel_launch(void* const* d_in, const int* in_sizes, int n_in,
                              void* d_out, int out_size, void* d_ws, size_t ws_size,
                              hipStream_t stream)
{
    const float* x   = (const float*)d_in[0];
    const float* px  = (const float*)d_in[1];
    const float* Wq  = (const float*)d_in[2];
    const float* Wk  = (const float*)d_in[3];
    const float* Wv  = (const float*)d_in[4];
    const float* Wo  = (const float*)d_in[5];
    const float* bo  = (const float*)d_in[6];
    const float* Wdw = (const float*)d_in[7];
    const float* bdw = (const float*)d_in[8];
    const float* Wp  = (const float*)d_in[9];
    float* out = (float*)d_out;
    int n = in_sizes[0] / DIMC;     // 4096
    int m = n / 4;                  // 1024

    float* ws  = (float*)d_ws;
    float* q    = ws;                                 // 512*n f32
    int*   x0i  = (int*)(q + (size_t)512*n);          // 8*m
    float* w1f  = (float*)(x0i + 8*m);                // 8*m
    _Float16* qhf  = (_Float16*)(w1f + 8*m);          // 8*n*64 f16   [h][i][d]
    _Float16* kt16 = qhf + (size_t)8*n*64;            // 2*8*m*64 f16 [s][h][j][d]
    _Float16* vt16 = kt16 + (size_t)16*m*64;          // 2*8*m*64 f16 [s][h][d][j]
    _Float16* aoh  = vt16 + (size_t)16*m*64;          // n*1024 f16   [i][c']
    _Float16* Woh  = aoh + (size_t)n*1024;            // 512*512 f16  [d][c]

    k_wcvt <<<128,              256, 0, stream>>>(Wo, Woh);
    k_qconv<<<dim3(8, n/64),    256, 0, stream>>>(x, px, Wq, q, qhf, n);
    k_off  <<<(NG*m + 255)/256, 256, 0, stream>>>(q, Wdw, bdw, Wp, x0i, w1f, n, m);
    k_kv   <<<2*8*(m/64),       256, 0, stream>>>(x, px, Wk, Wv, x0i, w1f, kt16, vt16, n, m);
    k_attn <<<2*8*(n/64),       256, 0, stream>>>(qhf, kt16, vt16, aoh, n, m);
    k_out  <<<dim3(n/64, 8),    256, 0, stream>>>(aoh, Woh, bo, out, n);
}

// Round 4
// 231.415 us; speedup vs baseline: 9.3022x; 1.2281x over previous
//
#include <hip/hip_runtime.h>
#include <math.h>

#define DIMC 512
#define NG 8

typedef _Float16 half8 __attribute__((ext_vector_type(8)));
typedef float f32x4 __attribute__((ext_vector_type(4)));

// ---------------- Wo f32 -> f16 cast (native [d][c] layout == MFMA B layout) ----------------
__global__ __launch_bounds__(256) void k_wcvt(const float* __restrict__ Wo, _Float16* __restrict__ Woh) {
    int idx = (blockIdx.x*256 + threadIdx.x) * 8;   // 128 blocks * 256 t * 8 = 262144
    float4 a = *(const float4*)&Wo[idx];
    float4 b = *(const float4*)&Wo[idx+4];
    union { _Float16 h[8]; uint4 v; } pk;
    pk.h[0]=(_Float16)a.x; pk.h[1]=(_Float16)a.y; pk.h[2]=(_Float16)a.z; pk.h[3]=(_Float16)a.w;
    pk.h[4]=(_Float16)b.x; pk.h[5]=(_Float16)b.y; pk.h[6]=(_Float16)b.z; pk.h[7]=(_Float16)b.w;
    *(uint4*)&Woh[idx] = pk.v;
}

// ---------------- q = grouped 1x1 conv over concat[prev_x, x] ----------------
// q fp32 channel-major (for offset net) + qh f16 [h][i][d] pre-scaled by 0.125 (for attention)
__global__ __launch_bounds__(256) void k_qconv(
    const float* __restrict__ x, const float* __restrict__ px,
    const float* __restrict__ Wq, float* __restrict__ q, _Float16* __restrict__ qh, int n)
{
    __shared__ float Xs[64][129];
    __shared__ float Wt[128][68];
    int g  = blockIdx.x;            // 0..7 == head
    int i0 = blockIdx.y * 64;
    int t  = threadIdx.x;
    const float* SRC = (g < 4) ? px : x;   // concat puts prev first
    int cbase = (g & 3) * 128;
#pragma unroll
    for (int r = 0; r < 8; ++r) {
        int f = t + 256*r;
        int i = f >> 5, kq = f & 31;
        float4 v = *(const float4*)&SRC[(size_t)(i0+i)*DIMC + cbase + kq*4];
        Xs[i][kq*4+0] = v.x; Xs[i][kq*4+1] = v.y; Xs[i][kq*4+2] = v.z; Xs[i][kq*4+3] = v.w;
    }
#pragma unroll
    for (int r = 0; r < 32; ++r) {
        int f = t + 256*r;
        int oc = f & 63, kk = f >> 6;
        Wt[kk][oc] = Wq[(size_t)(g*64+oc)*128 + kk];
    }
    __syncthreads();
    int lane = t & 63, w = t >> 6;         // lane = i, wave owns 16 oc
    float acc[16];
#pragma unroll
    for (int u = 0; u < 16; ++u) acc[u] = 0.f;
#pragma unroll 4
    for (int k = 0; k < 128; ++k) {
        float xv = Xs[lane][k];
#pragma unroll
        for (int q4 = 0; q4 < 4; ++q4) {
            float4 wv = *(const float4*)&Wt[k][w*16 + q4*4];   // broadcast
            acc[q4*4+0] += xv*wv.x; acc[q4*4+1] += xv*wv.y;
            acc[q4*4+2] += xv*wv.z; acc[q4*4+3] += xv*wv.w;
        }
    }
#pragma unroll
    for (int u = 0; u < 16; ++u)           // coalesced over lane=i
        q[(size_t)(g*64 + w*16 + u)*n + i0 + lane] = acc[u];
    // transpose through LDS -> qh f16 [h][i][d], scaled by 64^-0.5
    __syncthreads();
#pragma unroll
    for (int u = 0; u < 16; ++u) Xs[lane][w*16 + u] = acc[u];
    __syncthreads();
    {
        int i = t >> 2, qd = t & 3;
        union { _Float16 h[16]; uint4 v[2]; } pk;
#pragma unroll
        for (int v = 0; v < 16; ++v) pk.h[v] = (_Float16)(Xs[i][qd*16 + v] * 0.125f);
        uint4* dst = (uint4*)&qh[((size_t)g*n + i0 + i)*64 + qd*16];
        dst[0] = pk.v[0]; dst[1] = pk.v[1];
    }
}

// ---------------- offset net: depthwise conv s4 + GELU + 1x1 + tanh -> sample pos ----------------
// block = (g, 32 j's). Stage q tile to LDS, split (j x channel-group), LDS-reduce.
#define SW 136   // LDS row stride; tile covers cols [4*j0-1 , 4*j0+128] = 130 used
__global__ __launch_bounds__(256) void k_off(
    const float* __restrict__ q, const float* __restrict__ Wdw,
    const float* __restrict__ bdw, const float* __restrict__ Wp,
    int* __restrict__ x0i, float* __restrict__ w1f, int n, int m)
{
    __shared__ float qs[64][SW];
    __shared__ float part[8][36];
    int g  = blockIdx.x & 7;
    int j0 = (blockIdx.x >> 3) * 32;
    int t  = threadIdx.x;
    int lane = t & 63, wv = t >> 6;
    int pbase = 4*j0 - 1;
    // stage: 64 channel rows x 136 cols, contiguous 64-lane segments
#pragma unroll
    for (int rr = 0; rr < 16; ++rr) {
        int row = rr*4 + wv;
        const float* src = &q[(size_t)(g*64 + row)*n];
#pragma unroll
        for (int cc = 0; cc < 3; ++cc) {
            int col = cc*64 + lane;
            if (col < SW) {
                int p = pbase + col;
                qs[row][col] = (p >= 0 && p < n) ? src[p] : 0.f;
            }
        }
    }
    __syncthreads();
    // compute: thread = (j = t&31, cg = t>>5); 8 channels per thread
    int j  = t & 31, cg = t >> 5;
    float acc = 0.f;
#pragma unroll
    for (int cc = 0; cc < 8; ++cc) {
        int c = cg*8 + cc;
        float h = bdw[c];
#pragma unroll
        for (int tt = 0; tt < 6; ++tt)
            h += Wdw[c*6 + tt] * qs[c][4*j + tt];
        float ge = 0.5f * h * (1.0f + erff(h * 0.70710678118654752f));  // exact gelu
        acc += Wp[c] * ge;
    }
    part[cg][j] = acc;
    __syncthreads();
    if (t < 32) {
        float off = 0.f;
#pragma unroll
        for (int cg2 = 0; cg2 < 8; ++cg2) off += part[cg2][t];
        off = tanhf(off) * 4.0f;
        int jg = j0 + t;
        float vg  = 2.0f * ((float)jg + off) / (float)(m - 1) - 1.0f;
        float pos = ((vg + 1.0f) * (float)n - 1.0f) * 0.5f;
        float x0  = floorf(pos);
        x0i[g*m + jg] = (int)x0;
        w1f[g*m + jg] = pos - x0;
    }
}

// ---------------- grid-sample + k/v grouped 1x1 convs ----------------
// kt16 f16 [s][h][j][d]; vt16 f16 TRANSPOSED [s][h][d][j] (B-fragment friendly)
__global__ __launch_bounds__(256) void k_kv(
    const float* __restrict__ x, const float* __restrict__ px,
    const float* __restrict__ Wk, const float* __restrict__ Wv,
    const int* __restrict__ x0i, const float* __restrict__ w1f,
    _Float16* __restrict__ kt16, _Float16* __restrict__ vt16, int n, int m)
{
    __shared__ float Wks[64][65];
    __shared__ float Wvs[64][65];
    __shared__ float kvs[4][64];
    __shared__ int   x0s[64];
    __shared__ float w1s[64];
    int nj = m >> 6;
    int jc = blockIdx.x % nj;
    int g  = (blockIdx.x / nj) & 7;
    int s  = blockIdx.x / (nj*8);
    int t  = threadIdx.x;
    int j0 = jc*64;
#pragma unroll
    for (int r = 0; r < 16; ++r) {
        int f = t + 256*r;
        int oc = f >> 6, ic = f & 63;
        Wks[oc][ic] = Wk[(size_t)(g*64+oc)*64 + ic];
        Wvs[oc][ic] = Wv[(size_t)(g*64+oc)*64 + ic];
    }
    if (t < 64) { x0s[t] = x0i[g*m + j0 + t]; w1s[t] = w1f[g*m + j0 + t]; }
    __syncthreads();
    const float* SRC = s ? x : px;   // kv_in = concat([prev, cur], axis=0)
    int jl = t >> 6, c = t & 63;
    for (int jq = 0; jq < 16; ++jq) {
        int jloc = jq*4 + jl;
        int i0 = x0s[jloc];
        float wgt = w1s[jloc];
        float v0 = (i0 >= 0   && i0   < n) ? SRC[(size_t)i0*DIMC + g*64 + c]     : 0.f;
        float v1 = (i0+1 >= 0 && i0+1 < n) ? SRC[(size_t)(i0+1)*DIMC + g*64 + c] : 0.f;
        kvs[jl][c] = v0*(1.0f - wgt) + v1*wgt;
        __syncthreads();
        float ka = 0.f, va = 0.f;
#pragma unroll 8
        for (int ic = 0; ic < 64; ++ic) {
            float kvv = kvs[jl][ic];           // broadcast
            ka += Wks[c][ic]*kvv;
            va += Wvs[c][ic]*kvv;
        }
        kt16[((size_t)(s*8+g)*m + j0 + jloc)*64 + c]   = (_Float16)ka;  // coalesced
        vt16[((size_t)(s*8+g)*64 + c)*m + j0 + jloc]   = (_Float16)va;  // strided, tiny total
        __syncthreads();
    }
}

// ---------------- flash attention, f16 MFMA ----------------
__global__ __launch_bounds__(256, 2) void k_attn(
    const _Float16* __restrict__ qh, const _Float16* __restrict__ kt16,
    const _Float16* __restrict__ vt16, _Float16* __restrict__ aoh, int n, int m)
{
    __shared__ _Float16 Qs[64*72];   // [i][d] pad 72
    __shared__ _Float16 Ks[64*72];   // [j][d]
    __shared__ _Float16 Vs[64*72];   // [d][j]  (V transposed)
    __shared__ _Float16 Ps[64*72];   // [i][j]  per-wave-private 16-row strips
    int nit = n >> 6;
    int it = blockIdx.x % nit;
    int h  = (blockIdx.x / nit) & 7;
    int s  = blockIdx.x / (nit*8);
    int t  = threadIdx.x;
    int lane = t & 63, w = t >> 6;
    int l15 = lane & 15, quad = lane >> 4;
    int i0 = it*64;

    const _Float16* qb = &qh[((size_t)h*n + i0)*64];
#pragma unroll
    for (int r = 0; r < 2; ++r) {
        int c = t + 256*r;
        int i = c >> 3, oct = c & 7;
        *(uint4*)&Qs[i*72 + oct*8] = *(const uint4*)&qb[i*64 + oct*8];
    }

    const _Float16* kb = &kt16[(size_t)(s*8+h)*m*64];   // [j][d]
    const _Float16* vb = &vt16[(size_t)(s*8+h)*64*m];   // [d][j]

    float mrun[4], lrun[4];
#pragma unroll
    for (int r = 0; r < 4; ++r) { mrun[r] = -3.0e38f; lrun[r] = 0.f; }
    f32x4 oacc[4];
#pragma unroll
    for (int dt = 0; dt < 4; ++dt) oacc[dt] = (f32x4){0.f,0.f,0.f,0.f};

    int ntile = m >> 6;
    for (int tk = 0; tk < ntile; ++tk) {
        __syncthreads();
#pragma unroll
        for (int r = 0; r < 2; ++r) {
            int c = t + 256*r;
            int row = c >> 3, oct = c & 7;
            *(uint4*)&Ks[row*72 + oct*8] = *(const uint4*)&kb[(size_t)(tk*64 + row)*64 + oct*8];
            *(uint4*)&Vs[row*72 + oct*8] = *(const uint4*)&vb[(size_t)row*m + tk*64 + oct*8];
        }
        __syncthreads();

        f32x4 accs[4];
#pragma unroll
        for (int jt = 0; jt < 4; ++jt) accs[jt] = (f32x4){0.f,0.f,0.f,0.f};
#pragma unroll
        for (int ks = 0; ks < 2; ++ks) {
            half8 aq = *(const half8*)&Qs[(w*16 + l15)*72 + ks*32 + quad*8];
#pragma unroll
            for (int jt = 0; jt < 4; ++jt) {
                half8 bk = *(const half8*)&Ks[(jt*16 + l15)*72 + ks*32 + quad*8];
                accs[jt] = __builtin_amdgcn_mfma_f32_16x16x32_f16(aq, bk, accs[jt], 0, 0, 0);
            }
        }

        float mt[4], rs[4];
#pragma unroll
        for (int r = 0; r < 4; ++r) {
            float v = accs[0][r];
            v = fmaxf(v, accs[1][r]); v = fmaxf(v, accs[2][r]); v = fmaxf(v, accs[3][r]);
            mt[r] = v;
        }
#pragma unroll
        for (int msk = 1; msk <= 8; msk <<= 1)
#pragma unroll
            for (int r = 0; r < 4; ++r) mt[r] = fmaxf(mt[r], __shfl_xor(mt[r], msk, 64));
#pragma unroll
        for (int r = 0; r < 4; ++r) {
            float mnew = fmaxf(mrun[r], mt[r]);
            float al   = __expf(mrun[r] - mnew);
            mrun[r] = mnew;
            lrun[r] *= al;
            rs[r] = 0.f;
#pragma unroll
            for (int jt = 0; jt < 4; ++jt) {
                float p = __expf(accs[jt][r] - mnew);
                accs[jt][r] = p;
                rs[r] += p;
            }
#pragma unroll
            for (int dt = 0; dt < 4; ++dt) oacc[dt][r] *= al;
        }
#pragma unroll
        for (int msk = 1; msk <= 8; msk <<= 1)
#pragma unroll
            for (int r = 0; r < 4; ++r) rs[r] += __shfl_xor(rs[r], msk, 64);
#pragma unroll
        for (int r = 0; r < 4; ++r) lrun[r] += rs[r];

#pragma unroll
        for (int jt = 0; jt < 4; ++jt)
#pragma unroll
            for (int r = 0; r < 4; ++r)
                Ps[(w*16 + quad*4 + r)*72 + jt*16 + l15] = (_Float16)accs[jt][r];

#pragma unroll
        for (int ks = 0; ks < 2; ++ks) {
            half8 ap = *(const half8*)&Ps[(w*16 + l15)*72 + ks*32 + quad*8];
#pragma unroll
            for (int dt = 0; dt < 4; ++dt) {
                half8 bv = *(const half8*)&Vs[(dt*16 + l15)*72 + ks*32 + quad*8];
                oacc[dt] = __builtin_amdgcn_mfma_f32_16x16x32_f16(ap, bv, oacc[dt], 0, 0, 0);
            }
        }
    }

    // epilogue: normalize, store f16 (C layout: i = w*16+quad*4+r, d = dt*16+l15)
    float inv[4];
#pragma unroll
    for (int r = 0; r < 4; ++r) inv[r] = 1.0f / lrun[r];
#pragma unroll
    for (int dt = 0; dt < 4; ++dt)
#pragma unroll
        for (int r = 0; r < 4; ++r)
            aoh[(size_t)(i0 + w*16 + quad*4 + r)*1024 + s*512 + h*64 + dt*16 + l15]
                = (_Float16)(oacc[dt][r] * inv[r]);
}

// ---------------- Wo GEMM, f16 MFMA: out[i][d] = bo[d] + 0.5*sum_{c'} aoh[i][c']*Woh[d][c'&511] ----------------
__global__ __launch_bounds__(256) void k_out(
    const _Float16* __restrict__ aoh, const _Float16* __restrict__ Woh,
    const float* __restrict__ bo, float* __restrict__ out, int n)
{
    __shared__ _Float16 As[64*72];   // [i][k]
    __shared__ _Float16 Ws[64*72];   // [d][k]
    int i0 = blockIdx.x*64, d0 = blockIdx.y*64;
    int t = threadIdx.x;
    int lane = t & 63, w = t >> 6;
    int l15 = lane & 15, quad = lane >> 4;
    f32x4 oacc[4];
#pragma unroll
    for (int dt = 0; dt < 4; ++dt) oacc[dt] = (f32x4){0.f,0.f,0.f,0.f};

    for (int kc = 0; kc < 16; ++kc) {        // K' = 1024 in chunks of 64
        int cbase = (kc & 7) * 64;           // c = c' & 511 (chunks never straddle)
        __syncthreads();
#pragma unroll
        for (int r = 0; r < 2; ++r) {
            int c = t + 256*r;
            int row = c >> 3, oct = c & 7;
            *(uint4*)&As[row*72 + oct*8] = *(const uint4*)&aoh[(size_t)(i0+row)*1024 + kc*64 + oct*8];
            *(uint4*)&Ws[row*72 + oct*8] = *(const uint4*)&Woh[(size_t)(d0+row)*DIMC + cbase + oct*8];
        }
        __syncthreads();
#pragma unroll
        for (int ks = 0; ks < 2; ++ks) {
            half8 aq = *(const half8*)&As[(w*16 + l15)*72 + ks*32 + quad*8];
#pragma unroll
            for (int dt = 0; dt < 4; ++dt) {
                half8 bw = *(const half8*)&Ws[(dt*16 + l15)*72 + ks*32 + quad*8];
                oacc[dt] = __builtin_amdgcn_mfma_f32_16x16x32_f16(aq, bw, oacc[dt], 0, 0, 0);
            }
        }
    }
    // C layout: i = w*16+quad*4+r, d = dt*16+l15
#pragma unroll
    for (int dt = 0; dt < 4; ++dt) {
        float bias = bo[d0 + dt*16 + l15];
#pragma unroll
        for (int r = 0; r < 4; ++r)
            out[(size_t)(i0 + w*16 + quad*4 + r)*DIMC + d0 + dt*16 + l15]
                = bias + 0.5f*oacc[dt][r];
    }
}

extern "C" void kernel_launch(void* const* d_in, const int* in_sizes, int n_in,
                              void* d_out, int out_size, void* d_ws, size_t ws_size,
                              hipStream_t stream)
{
    const float* x   = (const float*)d_in[0];
    const float* px  = (const float*)d_in[1];
    const float* Wq  = (const float*)d_in[2];
    const float* Wk  = (const float*)d_in[3];
    const float* Wv  = (const float*)d_in[4];
    const float* Wo  = (const float*)d_in[5];
    const float* bo  = (const float*)d_in[6];
    const float* Wdw = (const float*)d_in[7];
    const float* bdw = (const float*)d_in[8];
    const float* Wp  = (const float*)d_in[9];
    float* out = (float*)d_out;
    int n = in_sizes[0] / DIMC;     // 4096
    int m = n / 4;                  // 1024

    float* ws  = (float*)d_ws;
    float* q    = ws;                                 // 512*n f32
    int*   x0i  = (int*)(q + (size_t)512*n);          // 8*m
    float* w1f  = (float*)(x0i + 8*m);                // 8*m
    _Float16* qhf  = (_Float16*)(w1f + 8*m);          // 8*n*64 f16   [h][i][d]
    _Float16* kt16 = qhf + (size_t)8*n*64;            // 2*8*m*64 f16 [s][h][j][d]
    _Float16* vt16 = kt16 + (size_t)16*m*64;          // 2*8*m*64 f16 [s][h][d][j]
    _Float16* aoh  = vt16 + (size_t)16*m*64;          // n*1024 f16   [i][c']
    _Float16* Woh  = aoh + (size_t)n*1024;            // 512*512 f16  [d][c]

    k_wcvt <<<128,              256, 0, stream>>>(Wo, Woh);
    k_qconv<<<dim3(8, n/64),    256, 0, stream>>>(x, px, Wq, q, qhf, n);
    k_off  <<<8*(m/32),         256, 0, stream>>>(q, Wdw, bdw, Wp, x0i, w1f, n, m);
    k_kv   <<<2*8*(m/64),       256, 0, stream>>>(x, px, Wk, Wv, x0i, w1f, kt16, vt16, n, m);
    k_attn <<<2*8*(n/64),       256, 0, stream>>>(qhf, kt16, vt16, aoh, n, m);
    k_out  <<<dim3(n/64, 8),    256, 0, stream>>>(aoh, Woh, bo, out, n);
}

// Round 6
// 214.716 us; speedup vs baseline: 10.0256x; 1.0778x over previous
//
#include <hip/hip_runtime.h>
#include <math.h>

#define DIMC 512
#define NG 8
// q pre-scale: 64^-0.5 * log2(e)  (so scores come out in exp2 units)
#define QSCALE 0.18033688011112042f
// softmax fixed shift: 5 * log2(e)
#define MSHIFT 7.2134752044448170f

typedef _Float16 half8 __attribute__((ext_vector_type(8)));
typedef __fp16 fp16x2 __attribute__((ext_vector_type(2)));
typedef float f32x4 __attribute__((ext_vector_type(4)));

// ---------------- Wo f32 -> f16 cast (native [d][c] layout == MFMA B layout) ----------------
__global__ __launch_bounds__(256) void k_wcvt(const float* __restrict__ Wo, _Float16* __restrict__ Woh) {
    int idx = (blockIdx.x*256 + threadIdx.x) * 8;
    float4 a = *(const float4*)&Wo[idx];
    float4 b = *(const float4*)&Wo[idx+4];
    union { _Float16 h[8]; uint4 v; } pk;
    pk.h[0]=(_Float16)a.x; pk.h[1]=(_Float16)a.y; pk.h[2]=(_Float16)a.z; pk.h[3]=(_Float16)a.w;
    pk.h[4]=(_Float16)b.x; pk.h[5]=(_Float16)b.y; pk.h[6]=(_Float16)b.z; pk.h[7]=(_Float16)b.w;
    *(uint4*)&Woh[idx] = pk.v;
}

// ---------------- q = grouped 1x1 conv over concat[prev_x, x] ----------------
__global__ __launch_bounds__(256) void k_qconv(
    const float* __restrict__ x, const float* __restrict__ px,
    const float* __restrict__ Wq, float* __restrict__ q, _Float16* __restrict__ qh, int n)
{
    __shared__ float Xs[64][129];
    __shared__ float Wt[128][68];
    int g  = blockIdx.x;            // 0..7 == head
    int i0 = blockIdx.y * 64;
    int t  = threadIdx.x;
    const float* SRC = (g < 4) ? px : x;   // concat puts prev first
    int cbase = (g & 3) * 128;
#pragma unroll
    for (int r = 0; r < 8; ++r) {
        int f = t + 256*r;
        int i = f >> 5, kq = f & 31;
        float4 v = *(const float4*)&SRC[(size_t)(i0+i)*DIMC + cbase + kq*4];
        Xs[i][kq*4+0] = v.x; Xs[i][kq*4+1] = v.y; Xs[i][kq*4+2] = v.z; Xs[i][kq*4+3] = v.w;
    }
#pragma unroll
    for (int r = 0; r < 32; ++r) {
        int f = t + 256*r;
        int oc = f & 63, kk = f >> 6;
        Wt[kk][oc] = Wq[(size_t)(g*64+oc)*128 + kk];
    }
    __syncthreads();
    int lane = t & 63, w = t >> 6;         // lane = i, wave owns 16 oc
    float acc[16];
#pragma unroll
    for (int u = 0; u < 16; ++u) acc[u] = 0.f;
#pragma unroll 4
    for (int k = 0; k < 128; ++k) {
        float xv = Xs[lane][k];
#pragma unroll
        for (int q4 = 0; q4 < 4; ++q4) {
            float4 wv = *(const float4*)&Wt[k][w*16 + q4*4];   // broadcast
            acc[q4*4+0] += xv*wv.x; acc[q4*4+1] += xv*wv.y;
            acc[q4*4+2] += xv*wv.z; acc[q4*4+3] += xv*wv.w;
        }
    }
#pragma unroll
    for (int u = 0; u < 16; ++u)           // coalesced over lane=i
        q[(size_t)(g*64 + w*16 + u)*n + i0 + lane] = acc[u];
    // transpose through LDS -> qh f16 [h][i][d], scaled by QSCALE
    __syncthreads();
#pragma unroll
    for (int u = 0; u < 16; ++u) Xs[lane][w*16 + u] = acc[u];
    __syncthreads();
    {
        int i = t >> 2, qd = t & 3;
        union { _Float16 h[16]; uint4 v[2]; } pk;
#pragma unroll
        for (int v = 0; v < 16; ++v) pk.h[v] = (_Float16)(Xs[i][qd*16 + v] * QSCALE);
        uint4* dst = (uint4*)&qh[((size_t)g*n + i0 + i)*64 + qd*16];
        dst[0] = pk.v[0]; dst[1] = pk.v[1];
    }
}

// ---------------- offset net ----------------
#define SW 136
__global__ __launch_bounds__(256) void k_off(
    const float* __restrict__ q, const float* __restrict__ Wdw,
    const float* __restrict__ bdw, const float* __restrict__ Wp,
    int* __restrict__ x0i, float* __restrict__ w1f, int n, int m)
{
    __shared__ float qs[64][SW];
    __shared__ float part[8][36];
    int g  = blockIdx.x & 7;
    int j0 = (blockIdx.x >> 3) * 32;
    int t  = threadIdx.x;
    int lane = t & 63, wv = t >> 6;
    int pbase = 4*j0 - 1;
#pragma unroll
    for (int rr = 0; rr < 16; ++rr) {
        int row = rr*4 + wv;
        const float* src = &q[(size_t)(g*64 + row)*n];
#pragma unroll
        for (int cc = 0; cc < 3; ++cc) {
            int col = cc*64 + lane;
            if (col < SW) {
                int p = pbase + col;
                qs[row][col] = (p >= 0 && p < n) ? src[p] : 0.f;
            }
        }
    }
    __syncthreads();
    int j  = t & 31, cg = t >> 5;
    float acc = 0.f;
#pragma unroll
    for (int cc = 0; cc < 8; ++cc) {
        int c = cg*8 + cc;
        float h = bdw[c];
#pragma unroll
        for (int tt = 0; tt < 6; ++tt)
            h += Wdw[c*6 + tt] * qs[c][4*j + tt];
        float ge = 0.5f * h * (1.0f + erff(h * 0.70710678118654752f));  // exact gelu
        acc += Wp[c] * ge;
    }
    part[cg][j] = acc;
    __syncthreads();
    if (t < 32) {
        float off = 0.f;
#pragma unroll
        for (int cg2 = 0; cg2 < 8; ++cg2) off += part[cg2][t];
        off = tanhf(off) * 4.0f;
        int jg = j0 + t;
        float vg  = 2.0f * ((float)jg + off) / (float)(m - 1) - 1.0f;
        float pos = ((vg + 1.0f) * (float)n - 1.0f) * 0.5f;
        float x0  = floorf(pos);
        x0i[g*m + jg] = (int)x0;
        w1f[g*m + jg] = pos - x0;
    }
}

// ---------------- grid-sample + k/v grouped 1x1 convs ----------------
__global__ __launch_bounds__(256) void k_kv(
    const float* __restrict__ x, const float* __restrict__ px,
    const float* __restrict__ Wk, const float* __restrict__ Wv,
    const int* __restrict__ x0i, const float* __restrict__ w1f,
    _Float16* __restrict__ kt16, _Float16* __restrict__ vt16, int n, int m)
{
    __shared__ float Wks[64][65];
    __shared__ float Wvs[64][65];
    __shared__ float kvs[4][64];
    __shared__ int   x0s[64];
    __shared__ float w1s[64];
    int nj = m >> 6;
    int jc = blockIdx.x % nj;
    int g  = (blockIdx.x / nj) & 7;
    int s  = blockIdx.x / (nj*8);
    int t  = threadIdx.x;
    int j0 = jc*64;
#pragma unroll
    for (int r = 0; r < 16; ++r) {
        int f = t + 256*r;
        int oc = f >> 6, ic = f & 63;
        Wks[oc][ic] = Wk[(size_t)(g*64+oc)*64 + ic];
        Wvs[oc][ic] = Wv[(size_t)(g*64+oc)*64 + ic];
    }
    if (t < 64) { x0s[t] = x0i[g*m + j0 + t]; w1s[t] = w1f[g*m + j0 + t]; }
    __syncthreads();
    const float* SRC = s ? x : px;
    int jl = t >> 6, c = t & 63;
    for (int jq = 0; jq < 16; ++jq) {
        int jloc = jq*4 + jl;
        int i0 = x0s[jloc];
        float wgt = w1s[jloc];
        float v0 = (i0 >= 0   && i0   < n) ? SRC[(size_t)i0*DIMC + g*64 + c]     : 0.f;
        float v1 = (i0+1 >= 0 && i0+1 < n) ? SRC[(size_t)(i0+1)*DIMC + g*64 + c] : 0.f;
        kvs[jl][c] = v0*(1.0f - wgt) + v1*wgt;
        __syncthreads();
        float ka = 0.f, va = 0.f;
#pragma unroll 8
        for (int ic = 0; ic < 64; ++ic) {
            float kvv = kvs[jl][ic];
            ka += Wks[c][ic]*kvv;
            va += Wvs[c][ic]*kvv;
        }
        kt16[((size_t)(s*8+g)*m + j0 + jloc)*64 + c]   = (_Float16)ka;
        vt16[((size_t)(s*8+g)*64 + c)*m + j0 + jloc]   = (_Float16)va;
        __syncthreads();
    }
}

// ---------------- flash attention v2: S^T trick, fixed-max softmax, in-register P^T ----------------
// Block = (s,h, 128-query tile); wave w owns i in [w*32, w*32+32).
// QK: A = K-tile (m=j), B = Q^T (n=i)  ->  S^T C-layout: lane(quad,l15) holds (j=jt*16+quad*4+r, i=it2*16+l15)
// PV: A = V^T (m=d), B = P^T (k=j, n=i) -> O^T C-layout: (d=dt*16+quad*4+r, i=it2*16+l15)
__global__ __launch_bounds__(256, 2) void k_attn(
    const _Float16* __restrict__ qh, const _Float16* __restrict__ kt16,
    const _Float16* __restrict__ vt16, _Float16* __restrict__ aoh, int n, int m)
{
    __shared__ _Float16 Qs[128*72];  // [i][d]; overlaid as O[i][d] at epilogue (wave-private strips)
    __shared__ _Float16 Ks[64*72];   // [j][d]
    __shared__ _Float16 Vs[64*72];   // [d][j]
    int nit = n >> 7;
    int it = blockIdx.x % nit;
    int h  = (blockIdx.x / nit) & 7;
    int s  = blockIdx.x / (nit*8);
    int t  = threadIdx.x;
    int lane = t & 63, w = t >> 6;
    int l15 = lane & 15, quad = lane >> 4;
    int i0 = it*128;

    // stage Q tile: 128 rows x 64 d
    const _Float16* qb = &qh[((size_t)h*n + i0)*64];
#pragma unroll
    for (int r = 0; r < 4; ++r) {
        int c = t + 256*r;
        int i = c >> 3, oct = c & 7;
        *(uint4*)&Qs[i*72 + oct*8] = *(const uint4*)&qb[i*64 + oct*8];
    }

    const _Float16* kb = &kt16[(size_t)(s*8+h)*m*64];   // [j][d]
    const _Float16* vb = &vt16[(size_t)(s*8+h)*64*m];   // [d][j]

    float lsum[2] = {0.f, 0.f};
    f32x4 oaccT[4][2];
#pragma unroll
    for (int dt = 0; dt < 4; ++dt)
#pragma unroll
        for (int i2 = 0; i2 < 2; ++i2) oaccT[dt][i2] = (f32x4){0.f,0.f,0.f,0.f};

    int ntile = m >> 6;
    for (int tk = 0; tk < ntile; ++tk) {
        __syncthreads();
#pragma unroll
        for (int r = 0; r < 2; ++r) {
            int c = t + 256*r;
            int row = c >> 3, oct = c & 7;
            *(uint4*)&Ks[row*72 + oct*8] = *(const uint4*)&kb[(size_t)(tk*64 + row)*64 + oct*8];
            *(uint4*)&Vs[row*72 + oct*8] = *(const uint4*)&vb[(size_t)row*m + tk*64 + oct*8];
        }
        __syncthreads();

        // --- S^T = K Q^T over wave's 32-i strip ---
        half8 aqv[2][4];   // A-frags from Ks: [ks][jt]
        half8 bqv[2][2];   // B-frags from Qs: [ks][it2]
#pragma unroll
        for (int ks = 0; ks < 2; ++ks) {
#pragma unroll
            for (int jt = 0; jt < 4; ++jt)
                aqv[ks][jt] = *(const half8*)&Ks[(jt*16 + l15)*72 + ks*32 + quad*8];
#pragma unroll
            for (int i2 = 0; i2 < 2; ++i2)
                bqv[ks][i2] = *(const half8*)&Qs[(w*32 + i2*16 + l15)*72 + ks*32 + quad*8];
        }
        f32x4 accs[4][2];
#pragma unroll
        for (int jt = 0; jt < 4; ++jt)
#pragma unroll
            for (int i2 = 0; i2 < 2; ++i2) accs[jt][i2] = (f32x4){0.f,0.f,0.f,0.f};
#pragma unroll
        for (int ks = 0; ks < 2; ++ks)
#pragma unroll
            for (int jt = 0; jt < 4; ++jt)
#pragma unroll
                for (int i2 = 0; i2 < 2; ++i2)
                    accs[jt][i2] = __builtin_amdgcn_mfma_f32_16x16x32_f16(
                        aqv[ks][jt], bqv[ks][i2], accs[jt][i2], 0, 0, 0);

        // --- p = exp2(t - MSHIFT) (== e^(s-5)); per-lane partial row sums ---
        int pki[4][2][2];   // packed f16 pairs: [jt][it2][r-pair]
#pragma unroll
        for (int jt = 0; jt < 4; ++jt)
#pragma unroll
            for (int i2 = 0; i2 < 2; ++i2) {
                f32x4 p;
#pragma unroll
                for (int r = 0; r < 4; ++r) p[r] = __builtin_amdgcn_exp2f(accs[jt][i2][r] - MSHIFT);
                lsum[i2] += (p[0]+p[1]) + (p[2]+p[3]);
                union { fp16x2 h; int i; } c0, c1;
                c0.h = __builtin_amdgcn_cvt_pkrtz(p[0], p[1]);
                c1.h = __builtin_amdgcn_cvt_pkrtz(p[2], p[3]);
                pki[jt][i2][0] = c0.i;
                pki[jt][i2][1] = c1.i;
            }

        // --- O^T += V^T P^T : build P^T B-frags in-register via shuffles ---
        half8 avv[2][4];   // A-frags from Vs: [ks][dt]
#pragma unroll
        for (int ks = 0; ks < 2; ++ks)
#pragma unroll
            for (int dt = 0; dt < 4; ++dt)
                avv[ks][dt] = *(const half8*)&Vs[(dt*16 + l15)*72 + ks*32 + quad*8];
        int qsel = quad >> 1;            // which src jt half this lane needs
        int qlow = (quad & 1) * 32;      // src lane base (srcquad = 2*(quad&1)+(pp>>1))
#pragma unroll
        for (int ks = 0; ks < 2; ++ks)
#pragma unroll
            for (int i2 = 0; i2 < 2; ++i2) {
                union { half8 h; int i4[4]; } bp;
#pragma unroll
                for (int pp = 0; pp < 4; ++pp) {
                    int srcLane = qlow + (pp >> 1)*16 + l15;
                    int v0 = __shfl(pki[2*ks  ][i2][pp & 1], srcLane, 64);
                    int v1 = __shfl(pki[2*ks+1][i2][pp & 1], srcLane, 64);
                    bp.i4[pp] = qsel ? v1 : v0;
                }
#pragma unroll
                for (int dt = 0; dt < 4; ++dt)
                    oaccT[dt][i2] = __builtin_amdgcn_mfma_f32_16x16x32_f16(
                        avv[ks][dt], bp.h, oaccT[dt][i2], 0, 0, 0);
            }
    }

    // --- finalize: reduce l across quads (once), normalize, transpose via Qs overlay, store ---
#pragma unroll
    for (int i2 = 0; i2 < 2; ++i2) {
        lsum[i2] += __shfl_xor(lsum[i2], 16, 64);
        lsum[i2] += __shfl_xor(lsum[i2], 32, 64);
    }
    float inv[2] = {1.0f / lsum[0], 1.0f / lsum[1]};
    // wave-private strip of Qs: rows w*32 .. w*32+31 — no barrier needed
#pragma unroll
    for (int dt = 0; dt < 4; ++dt)
#pragma unroll
        for (int i2 = 0; i2 < 2; ++i2)
#pragma unroll
            for (int r = 0; r < 4; ++r)
                Qs[(w*32 + i2*16 + l15)*72 + dt*16 + quad*4 + r]
                    = (_Float16)(oaccT[dt][i2][r] * inv[i2]);
    // coalesced-ish store: lane pair per row, 32 halfwords each
    {
        int row = w*32 + (lane >> 1);
        int dbase = (lane & 1) * 32;
        size_t gbase = (size_t)(i0 + row)*1024 + s*512 + h*64 + dbase;
#pragma unroll
        for (int k2 = 0; k2 < 4; ++k2) {
            uint4 v = *(uint4*)&Qs[row*72 + dbase + k2*8];
            *(uint4*)&aoh[gbase + k2*8] = v;
        }
    }
}

// ---------------- Wo GEMM, f16 MFMA ----------------
__global__ __launch_bounds__(256) void k_out(
    const _Float16* __restrict__ aoh, const _Float16* __restrict__ Woh,
    const float* __restrict__ bo, float* __restrict__ out, int n)
{
    __shared__ _Float16 As[64*72];   // [i][k]
    __shared__ _Float16 Ws[64*72];   // [d][k]
    int i0 = blockIdx.x*64, d0 = blockIdx.y*64;
    int t = threadIdx.x;
    int lane = t & 63, w = t >> 6;
    int l15 = lane & 15, quad = lane >> 4;
    f32x4 oacc[4];
#pragma unroll
    for (int dt = 0; dt < 4; ++dt) oacc[dt] = (f32x4){0.f,0.f,0.f,0.f};

    for (int kc = 0; kc < 16; ++kc) {
        int cbase = (kc & 7) * 64;
        __syncthreads();
#pragma unroll
        for (int r = 0; r < 2; ++r) {
            int c = t + 256*r;
            int row = c >> 3, oct = c & 7;
            *(uint4*)&As[row*72 + oct*8] = *(const uint4*)&aoh[(size_t)(i0+row)*1024 + kc*64 + oct*8];
            *(uint4*)&Ws[row*72 + oct*8] = *(const uint4*)&Woh[(size_t)(d0+row)*DIMC + cbase + oct*8];
        }
        __syncthreads();
#pragma unroll
        for (int ks = 0; ks < 2; ++ks) {
            half8 aq = *(const half8*)&As[(w*16 + l15)*72 + ks*32 + quad*8];
#pragma unroll
            for (int dt = 0; dt < 4; ++dt) {
                half8 bw = *(const half8*)&Ws[(dt*16 + l15)*72 + ks*32 + quad*8];
                oacc[dt] = __builtin_amdgcn_mfma_f32_16x16x32_f16(aq, bw, oacc[dt], 0, 0, 0);
            }
        }
    }
#pragma unroll
    for (int dt = 0; dt < 4; ++dt) {
        float bias = bo[d0 + dt*16 + l15];
#pragma unroll
        for (int r = 0; r < 4; ++r)
            out[(size_t)(i0 + w*16 + quad*4 + r)*DIMC + d0 + dt*16 + l15]
                = bias + 0.5f*oacc[dt][r];
    }
}

extern "C" void kernel_launch(void* const* d_in, const int* in_sizes, int n_in,
                              void* d_out, int out_size, void* d_ws, size_t ws_size,
                              hipStream_t stream)
{
    const float* x   = (const float*)d_in[0];
    const float* px  = (const float*)d_in[1];
    const float* Wq  = (const float*)d_in[2];
    const float* Wk  = (const float*)d_in[3];
    const float* Wv  = (const float*)d_in[4];
    const float* Wo  = (const float*)d_in[5];
    const float* bo  = (const float*)d_in[6];
    const float* Wdw = (const float*)d_in[7];
    const float* bdw = (const float*)d_in[8];
    const float* Wp  = (const float*)d_in[9];
    float* out = (float*)d_out;
    int n = in_sizes[0] / DIMC;     // 4096
    int m = n / 4;                  // 1024

    float* ws  = (float*)d_ws;
    float* q    = ws;                                 // 512*n f32
    int*   x0i  = (int*)(q + (size_t)512*n);          // 8*m
    float* w1f  = (float*)(x0i + 8*m);                // 8*m
    _Float16* qhf  = (_Float16*)(w1f + 8*m);          // 8*n*64 f16   [h][i][d]
    _Float16* kt16 = qhf + (size_t)8*n*64;            // 2*8*m*64 f16 [s][h][j][d]
    _Float16* vt16 = kt16 + (size_t)16*m*64;          // 2*8*m*64 f16 [s][h][d][j]
    _Float16* aoh  = vt16 + (size_t)16*m*64;          // n*1024 f16   [i][c']
    _Float16* Woh  = aoh + (size_t)n*1024;            // 512*512 f16  [d][c]

    k_wcvt <<<128,              256, 0, stream>>>(Wo, Woh);
    k_qconv<<<dim3(8, n/64),    256, 0, stream>>>(x, px, Wq, q, qhf, n);
    k_off  <<<8*(m/32),         256, 0, stream>>>(q, Wdw, bdw, Wp, x0i, w1f, n, m);
    k_kv   <<<2*8*(m/64),       256, 0, stream>>>(x, px, Wk, Wv, x0i, w1f, kt16, vt16, n, m);
    k_attn <<<2*8*(n/128),      256, 0, stream>>>(qhf, kt16, vt16, aoh, n, m);
    k_out  <<<dim3(n/64, 8),    256, 0, stream>>>(aoh, Woh, bo, out, n);
}